// Round 9
// baseline (330.167 us; speedup 1.0000x reference)
//
#include <hip/hip_runtime.h>

typedef __bf16 bf16;
typedef __bf16 bf16x8 __attribute__((ext_vector_type(8)));
typedef __bf16 bf16x4 __attribute__((ext_vector_type(4)));
typedef float floatx4 __attribute__((ext_vector_type(4)));

#define MFMA(a, b, c) __builtin_amdgcn_mfma_f32_16x16x32_bf16((a), (b), (c), 0, 0, 0)

__device__ inline bf16x8 load8(const bf16* p) { return *(const bf16x8*)(p); }

__device__ inline void store_c(bf16* p, float v) { *p = (bf16)v; }
__device__ inline void store_c(float* p, float v) { *p = v; }

// Async global->LDS, 16B/lane; dest = wave-uniform base + lane*16.
__device__ inline void gload_lds(const bf16* g, bf16* l) {
    __builtin_amdgcn_global_load_lds(
        (const __attribute__((address_space(1))) void*)(g),
        (__attribute__((address_space(3))) void*)(l), 16, 0, 0);
}

// ---------------- fp32 -> bf16 bulk convert (7 tensors, one dispatch) ------
struct CvtArgs {
    const float* src[7];
    bf16* dst[7];
    int n[7];
};
__global__ __launch_bounds__(256) void cvt_bf16(CvtArgs a) {
    const int t = blockIdx.y;
    const int i = (blockIdx.x * 256 + threadIdx.x) * 8;
    if (i >= a.n[t]) return;
    const float4 u = *(const float4*)(a.src[t] + i);
    const float4 v = *(const float4*)(a.src[t] + i + 4);
    bf16x8 r;
    r[0] = (bf16)u.x; r[1] = (bf16)u.y; r[2] = (bf16)u.z; r[3] = (bf16)u.w;
    r[4] = (bf16)v.x; r[5] = (bf16)v.y; r[6] = (bf16)v.z; r[7] = (bf16)v.w;
    *(bf16x8*)(a.dst[t] + i) = r;
}

// ---------------- m97-style LDS GEMM (validated round 8) -------------------
template <typename TC>
__device__ inline void gemm_core(const bf16* __restrict__ A, const bf16* __restrict__ W,
                                 const float* __restrict__ bias, TC* __restrict__ C,
                                 bool TR) {
    __shared__ bf16 As[2][128][32];
    __shared__ bf16 Bs[2][128][32];

    const int tid = threadIdx.x;
    const int wv = tid >> 6, lane = tid & 63;
    const int quad = lane >> 4, lo = lane & 15;
    const int wm = wv >> 1, wn = wv & 1;
    const int Ar0 = blockIdx.y * 128, Br0 = blockIdx.x * 128;

    const int srow = lane >> 2, sseg = (lane & 3) ^ (srow & 3);
    const bf16* Ag = A + (size_t)(Ar0 + srow) * 1024 + sseg * 8;
    const bf16* Bg = W + (size_t)(Br0 + srow) * 1024 + sseg * 8;

    auto stage = [&](int buf, int k0) {
#pragma unroll
        for (int c = 2 * wv; c < 2 * wv + 2; c++) {
            gload_lds(Ag + (size_t)c * 16 * 1024 + k0, &As[buf][c * 16][0]);
            gload_lds(Bg + (size_t)c * 16 * 1024 + k0, &Bs[buf][c * 16][0]);
        }
    };

    floatx4 acc[4][4] = {};
    const int rs = (quad ^ (lo & 3)) * 8;

    stage(0, 0);
    for (int k0 = 0; k0 < 1024; k0 += 32) {
        const int buf = (k0 >> 5) & 1;
        __syncthreads();
        if (k0 + 32 < 1024) stage(buf ^ 1, k0 + 32);

        bf16x8 a[4], b[4];
#pragma unroll
        for (int i = 0; i < 4; i++) a[i] = load8(&As[buf][wm * 64 + i * 16 + lo][rs]);
#pragma unroll
        for (int j = 0; j < 4; j++) b[j] = load8(&Bs[buf][wn * 64 + j * 16 + lo][rs]);
#pragma unroll
        for (int i = 0; i < 4; i++)
#pragma unroll
            for (int j = 0; j < 4; j++) acc[i][j] = MFMA(a[i], b[j], acc[i][j]);
    }

#pragma unroll
    for (int i = 0; i < 4; i++) {
#pragma unroll
        for (int j = 0; j < 4; j++) {
#pragma unroll
            for (int r = 0; r < 4; r++) {
                const int m = Ar0 + wm * 64 + i * 16 + quad * 4 + r;
                const int n = Br0 + wn * 64 + j * 16 + lo;
                const float v = acc[i][j][r] + bias[n];
                if (!TR) {
                    store_c(C + (size_t)m * 1024 + n, v);
                } else {
                    store_c(C + (size_t)(n >> 6) * (64 * 4096) + (size_t)(n & 63) * 4096 + m, v);
                }
            }
        }
    }
}

__global__ __launch_bounds__(256) void gemm_qkv(
    const bf16* __restrict__ qb, const bf16* __restrict__ kb, const bf16* __restrict__ vb,
    const bf16* __restrict__ Wq, const bf16* __restrict__ Wk, const bf16* __restrict__ Wv,
    const float* __restrict__ bq, const float* __restrict__ bk, const float* __restrict__ bv,
    bf16* __restrict__ Q, bf16* __restrict__ Kp, bf16* __restrict__ Vt) {
    if (blockIdx.z == 0)
        gemm_core<bf16>(qb, Wq, bq, Q, false);
    else if (blockIdx.z == 1)
        gemm_core<bf16>(kb, Wk, bk, Kp, false);
    else
        gemm_core<bf16>(vb, Wv, bv, Vt, true);  // Vt[h][d][s]
}

__global__ __launch_bounds__(256) void gemm_o(const bf16* __restrict__ O,
                                              const bf16* __restrict__ Wo,
                                              const float* __restrict__ bo,
                                              float* __restrict__ out) {
    gemm_core<float>(O, Wo, bo, out, false);
}

// ---------------- flash v4: r7 body + split-K over blockIdx.z --------------
// Fixed-max softmax partials are linear: each split accumulates unnormalized
// fp32 O and l via device-scope atomicAdd; normalize kernel divides at the end.
// Grid (16h, 32qb, 2split) = 1024 blocks -> 3 blocks/CU resident (LDS 51.2KB),
// 12 waves/CU vs 8 before (round-8 post-mortem: grid-limited occupancy).
__global__ __launch_bounds__(256) void flash_attn4(const bf16* __restrict__ Q,
                                                   const bf16* __restrict__ Kmat,
                                                   const bf16* __restrict__ Vt,
                                                   float* __restrict__ Of,
                                                   float* __restrict__ Lf) {
    __shared__ bf16 Ks[2][64][64];
    __shared__ bf16 Vs[2][64][64];
    __shared__ bf16 Ps[4][2][16][72];

    const int tid = threadIdx.x;
    const int wv = tid >> 6;
    const int lane = tid & 63;
    const int quad = lane >> 4, lo = lane & 15;
    const int h = blockIdx.x;
    const int qb = blockIdx.y;
    const int split = blockIdx.z;
    const int DM = 1024;
    const int q0 = qb * 128 + wv * 32;

    bf16x8 aQ[2][2];
#pragma unroll
    for (int qs = 0; qs < 2; qs++) {
        const bf16* qp = Q + (size_t)(q0 + qs * 16 + lo) * DM + h * 64 + quad * 8;
        aQ[qs][0] = load8(qp);
        aQ[qs][1] = load8(qp + 32);
    }

    floatx4 Oacc[2][4] = {};
    float lsum[2][4] = {{0.f}};

    const int srow = lane >> 3, sseg = (lane & 7) ^ srow;
    const bf16* Kg = Kmat + (size_t)srow * DM + h * 64 + sseg * 8;
    const bf16* Vg = Vt + (size_t)h * 64 * 4096 + (size_t)srow * 4096 + sseg * 8;

    auto stage = [&](int buf, int kb2) {
#pragma unroll
        for (int c = 2 * wv; c < 2 * wv + 2; c++) {
            gload_lds(Kg + (size_t)(kb2 + c * 8) * DM, &Ks[buf][c * 8][0]);
            gload_lds(Vg + (size_t)(c * 8) * 4096 + kb2, &Vs[buf][c * 8][0]);
        }
    };

    const float C_SCALE = 0.18033688011112043f;  // 0.125 * log2(e)
    const float C_BIAS = 23.083120654223415f;    // 16 * log2(e)
    const int sw = lo & 7;

    const int kbeg = split * 2048, kend = kbeg + 2048;
    stage(0, kbeg);
    for (int kb2 = kbeg; kb2 < kend; kb2 += 64) {
        const int buf = (kb2 >> 6) & 1;
        __syncthreads();
        if (kb2 + 64 < kend) stage(buf ^ 1, kb2 + 64);

        floatx4 sc[2][4];
#pragma unroll
        for (int t = 0; t < 4; t++) {
            const bf16* krow = &Ks[buf][t * 16 + lo][0];
            const bf16x8 b0 = load8(krow + ((quad ^ sw) * 8));
            const bf16x8 b1 = load8(krow + (((quad + 4) ^ sw) * 8));
#pragma unroll
            for (int qs = 0; qs < 2; qs++) {
                floatx4 z = {};
                z = MFMA(aQ[qs][0], b0, z);
                sc[qs][t] = MFMA(aQ[qs][1], b1, z);
            }
        }

#pragma unroll
        for (int qs = 0; qs < 2; qs++)
#pragma unroll
            for (int t = 0; t < 4; t++)
#pragma unroll
                for (int r = 0; r < 4; r++) {
                    const float p = exp2f(fmaf(sc[qs][t][r], C_SCALE, -C_BIAS));
                    lsum[qs][r] += p;
                    Ps[wv][qs][quad * 4 + r][t * 16 + lo] = (bf16)p;
                }

#pragma unroll
        for (int kk = 0; kk < 2; kk++) {
            bf16x8 aP[2];
            aP[0] = load8(&Ps[wv][0][lo][kk * 32 + quad * 8]);
            aP[1] = load8(&Ps[wv][1][lo][kk * 32 + quad * 8]);
#pragma unroll
            for (int nt = 0; nt < 4; nt++) {
                const bf16x8 bV = load8(&Vs[buf][nt * 16 + lo][(((kk * 4 + quad) ^ sw) * 8)]);
                Oacc[0][nt] = MFMA(aP[0], bV, Oacc[0][nt]);
                Oacc[1][nt] = MFMA(aP[1], bV, Oacc[1][nt]);
            }
        }
    }

    // reduce l over the 16 cols (lo lanes) per quad-row
#pragma unroll
    for (int qs = 0; qs < 2; qs++)
#pragma unroll
        for (int r = 0; r < 4; r++) {
            float v = lsum[qs][r];
#pragma unroll
            for (int m = 1; m < 16; m <<= 1) v += __shfl_xor(v, m, 64);
            lsum[qs][r] = v;
        }

    // accumulate partials (device-scope atomics; 2 writers/address)
#pragma unroll
    for (int qs = 0; qs < 2; qs++)
#pragma unroll
        for (int nt = 0; nt < 4; nt++)
#pragma unroll
            for (int r = 0; r < 4; r++) {
                const int q = q0 + qs * 16 + quad * 4 + r;
                atomicAdd(&Of[(size_t)q * DM + h * 64 + nt * 16 + lo], Oacc[qs][nt][r]);
            }
    if (lo == 0) {
#pragma unroll
        for (int qs = 0; qs < 2; qs++)
#pragma unroll
            for (int r = 0; r < 4; r++)
                atomicAdd(&Lf[h * 4096 + q0 + qs * 16 + quad * 4 + r], lsum[qs][r]);
    }
}

// Ob[q][h*64+d] = Of[q][h*64+d] / Lf[h][q]
__global__ __launch_bounds__(256) void normalize(const float* __restrict__ Of,
                                                 const float* __restrict__ Lf,
                                                 bf16* __restrict__ Ob) {
    const int q = blockIdx.x;
    const int t = threadIdx.x;
    const int h = t >> 4;  // (t*4)>>6
    const float inv = 1.0f / Lf[h * 4096 + q];
    const float4 v = ((const float4*)(Of + (size_t)q * 1024))[t];
    bf16x4 r;
    r[0] = (bf16)(v.x * inv); r[1] = (bf16)(v.y * inv);
    r[2] = (bf16)(v.z * inv); r[3] = (bf16)(v.w * inv);
    ((bf16x4*)(Ob + (size_t)q * 1024))[t] = r;
}

extern "C" void kernel_launch(void* const* d_in, const int* in_sizes, int n_in,
                              void* d_out, int out_size, void* d_ws, size_t ws_size,
                              hipStream_t stream) {
    const float* query = (const float*)d_in[0];
    const float* key_i = (const float*)d_in[1];
    const float* value = (const float*)d_in[2];
    const float* Wq = (const float*)d_in[3];
    const float* bq = (const float*)d_in[4];
    const float* Wk = (const float*)d_in[5];
    const float* bk = (const float*)d_in[6];
    const float* Wv = (const float*)d_in[7];
    const float* bv = (const float*)d_in[8];
    const float* Wo = (const float*)d_in[9];
    const float* bo = (const float*)d_in[10];

    char* base = (char*)d_ws;
    const size_t MB = 1 << 20;
    // live ranges: qb/kb/vb + Wq/Wk/Wv die after gemm_qkv; Of/l/Ob reuse them.
    bf16* qb  = (bf16*)(base);             // [0,8M)
    bf16* kb  = (bf16*)(base + 8 * MB);    // [8,16M)
    bf16* vb  = (bf16*)(base + 16 * MB);   // [16,24M)
    bf16* Wqb = (bf16*)(base + 24 * MB);   // [24,26M)
    bf16* Wkb = (bf16*)(base + 26 * MB);   // [26,28M)
    bf16* Wvb = (bf16*)(base + 28 * MB);   // [28,30M)
    bf16* Wob = (bf16*)(base + 30 * MB);   // [30,32M)  LIVE until gemm_o
    bf16* Q   = (bf16*)(base + 32 * MB);   // [32,40M)
    bf16* K   = (bf16*)(base + 40 * MB);   // [40,48M)
    bf16* Vt  = (bf16*)(base + 48 * MB);   // [48,56M)
    float* Of = (float*)(base);            // [0,16M)   over qb,kb (dead)
    float* Lf = (float*)(base + 16 * MB);  // 256KB     over vb (dead)
    bf16* Ob  = (bf16*)(base + 17 * MB);   // [17,25M)  over vb/Wqb (dead)

    CvtArgs ca;
    const int SZ = 4096 * 1024, WZ = 1024 * 1024;
    ca.src[0] = query; ca.dst[0] = qb;  ca.n[0] = SZ;
    ca.src[1] = key_i; ca.dst[1] = kb;  ca.n[1] = SZ;
    ca.src[2] = value; ca.dst[2] = vb;  ca.n[2] = SZ;
    ca.src[3] = Wq;    ca.dst[3] = Wqb; ca.n[3] = WZ;
    ca.src[4] = Wk;    ca.dst[4] = Wkb; ca.n[4] = WZ;
    ca.src[5] = Wv;    ca.dst[5] = Wvb; ca.n[5] = WZ;
    ca.src[6] = Wo;    ca.dst[6] = Wob; ca.n[6] = WZ;
    cvt_bf16<<<dim3(2048, 7), 256, 0, stream>>>(ca);

    gemm_qkv<<<dim3(8, 32, 3), 256, 0, stream>>>(qb, kb, vb, Wqb, Wkb, Wvb,
                                                 bq, bk, bv, Q, K, Vt);
    // zero the fp32 O/l accumulators (qb/kb/vb consumed above; stream-ordered)
    hipMemsetAsync(base, 0, 16 * MB + 4096 * 16 * sizeof(float), stream);

    flash_attn4<<<dim3(16, 32, 2), 256, 0, stream>>>(Q, K, Vt, Of, Lf);
    normalize<<<4096, 256, 0, stream>>>(Of, Lf, Ob);
    gemm_o<<<dim3(8, 32), 256, 0, stream>>>(Ob, Wob, bo, (float*)d_out);
}

// Round 10
// 294.604 us; speedup vs baseline: 1.1207x; 1.1207x over previous
//
#include <hip/hip_runtime.h>

typedef __bf16 bf16;
typedef __bf16 bf16x8 __attribute__((ext_vector_type(8)));
typedef __bf16 bf16x4 __attribute__((ext_vector_type(4)));
typedef float floatx4 __attribute__((ext_vector_type(4)));

#define MFMA(a, b, c) __builtin_amdgcn_mfma_f32_16x16x32_bf16((a), (b), (c), 0, 0, 0)

__device__ inline bf16x8 load8(const bf16* p) { return *(const bf16x8*)(p); }

__device__ inline void store_c(bf16* p, float v) { *p = (bf16)v; }
__device__ inline void store_c(float* p, float v) { *p = v; }

// Async global->LDS, 16B/lane; dest = wave-uniform base + lane*16.
__device__ inline void gload_lds(const bf16* g, bf16* l) {
    __builtin_amdgcn_global_load_lds(
        (const __attribute__((address_space(1))) void*)(g),
        (__attribute__((address_space(3))) void*)(l), 16, 0, 0);
}

// ---------------- fp32 -> bf16 bulk convert (7 tensors, one dispatch) ------
struct CvtArgs {
    const float* src[7];
    bf16* dst[7];
    int n[7];
};
__global__ __launch_bounds__(256) void cvt_bf16(CvtArgs a) {
    const int t = blockIdx.y;
    const int i = (blockIdx.x * 256 + threadIdx.x) * 8;
    if (i >= a.n[t]) return;
    const float4 u = *(const float4*)(a.src[t] + i);
    const float4 v = *(const float4*)(a.src[t] + i + 4);
    bf16x8 r;
    r[0] = (bf16)u.x; r[1] = (bf16)u.y; r[2] = (bf16)u.z; r[3] = (bf16)u.w;
    r[4] = (bf16)v.x; r[5] = (bf16)v.y; r[6] = (bf16)v.z; r[7] = (bf16)v.w;
    *(bf16x8*)(a.dst[t] + i) = r;
}

// ---------------- m97-style LDS GEMM (validated round 8) -------------------
template <typename TC>
__device__ inline void gemm_core(const bf16* __restrict__ A, const bf16* __restrict__ W,
                                 const float* __restrict__ bias, TC* __restrict__ C,
                                 bool TR) {
    __shared__ bf16 As[2][128][32];
    __shared__ bf16 Bs[2][128][32];

    const int tid = threadIdx.x;
    const int wv = tid >> 6, lane = tid & 63;
    const int quad = lane >> 4, lo = lane & 15;
    const int wm = wv >> 1, wn = wv & 1;
    const int Ar0 = blockIdx.y * 128, Br0 = blockIdx.x * 128;

    const int srow = lane >> 2, sseg = (lane & 3) ^ (srow & 3);
    const bf16* Ag = A + (size_t)(Ar0 + srow) * 1024 + sseg * 8;
    const bf16* Bg = W + (size_t)(Br0 + srow) * 1024 + sseg * 8;

    auto stage = [&](int buf, int k0) {
#pragma unroll
        for (int c = 2 * wv; c < 2 * wv + 2; c++) {
            gload_lds(Ag + (size_t)c * 16 * 1024 + k0, &As[buf][c * 16][0]);
            gload_lds(Bg + (size_t)c * 16 * 1024 + k0, &Bs[buf][c * 16][0]);
        }
    };

    floatx4 acc[4][4] = {};
    const int rs = (quad ^ (lo & 3)) * 8;

    stage(0, 0);
    for (int k0 = 0; k0 < 1024; k0 += 32) {
        const int buf = (k0 >> 5) & 1;
        __syncthreads();
        if (k0 + 32 < 1024) stage(buf ^ 1, k0 + 32);

        bf16x8 a[4], b[4];
#pragma unroll
        for (int i = 0; i < 4; i++) a[i] = load8(&As[buf][wm * 64 + i * 16 + lo][rs]);
#pragma unroll
        for (int j = 0; j < 4; j++) b[j] = load8(&Bs[buf][wn * 64 + j * 16 + lo][rs]);
#pragma unroll
        for (int i = 0; i < 4; i++)
#pragma unroll
            for (int j = 0; j < 4; j++) acc[i][j] = MFMA(a[i], b[j], acc[i][j]);
    }

#pragma unroll
    for (int i = 0; i < 4; i++) {
#pragma unroll
        for (int j = 0; j < 4; j++) {
#pragma unroll
            for (int r = 0; r < 4; r++) {
                const int m = Ar0 + wm * 64 + i * 16 + quad * 4 + r;
                const int n = Br0 + wn * 64 + j * 16 + lo;
                const float v = acc[i][j][r] + bias[n];
                if (!TR) {
                    store_c(C + (size_t)m * 1024 + n, v);
                } else {
                    store_c(C + (size_t)(n >> 6) * (64 * 4096) + (size_t)(n & 63) * 4096 + m, v);
                }
            }
        }
    }
}

__global__ __launch_bounds__(256) void gemm_qkv(
    const bf16* __restrict__ qb, const bf16* __restrict__ kb, const bf16* __restrict__ vb,
    const bf16* __restrict__ Wq, const bf16* __restrict__ Wk, const bf16* __restrict__ Wv,
    const float* __restrict__ bq, const float* __restrict__ bk, const float* __restrict__ bv,
    bf16* __restrict__ Q, bf16* __restrict__ Kp, bf16* __restrict__ Vt) {
    if (blockIdx.z == 0)
        gemm_core<bf16>(qb, Wq, bq, Q, false);
    else if (blockIdx.z == 1)
        gemm_core<bf16>(kb, Wk, bk, Kp, false);
    else
        gemm_core<bf16>(vb, Wv, bv, Vt, true);  // Vt[h][d][s]
}

__global__ __launch_bounds__(256) void gemm_o(const bf16* __restrict__ O,
                                              const bf16* __restrict__ Wo,
                                              const float* __restrict__ bo,
                                              float* __restrict__ out) {
    gemm_core<float>(O, Wo, bo, out, false);
}

// ---------------- flash v5: transposed QK^T (S^T = K*Q^T) ------------------
// r9 post-mortem: jointly VALU+DS bound (32 scalar ds_write_b16 + 32 scalar
// lsum adds per iter). S^T puts 4 CONSECUTIVE keys in each lane (row=key),
// so P-writes become 8 ds_write_b64, and l comes from MFMA(aP, ones) in
// C-layout (row=q) -- no scalar adds, no end shuffles. A/B frag layouts are
// identical, so all LDS reads are byte-identical to the validated r8 kernel.
__global__ __launch_bounds__(256) void flash_attn5(const bf16* __restrict__ Q,
                                                   const bf16* __restrict__ Kmat,
                                                   const bf16* __restrict__ Vt,
                                                   bf16* __restrict__ O) {
    __shared__ bf16 Ks[2][64][64];
    __shared__ bf16 Vs[2][64][64];
    __shared__ __align__(16) bf16 Ps[4][2][16][72];

    const int tid = threadIdx.x;
    const int wv = tid >> 6;
    const int lane = tid & 63;
    const int quad = lane >> 4, lo = lane & 15;
    const int h = blockIdx.x;
    const int qb = blockIdx.y;
    const int DM = 1024;
    const int q0 = qb * 128 + wv * 32;

    bf16x8 aQ[2][2];
#pragma unroll
    for (int qs = 0; qs < 2; qs++) {
        const bf16* qp = Q + (size_t)(q0 + qs * 16 + lo) * DM + h * 64 + quad * 8;
        aQ[qs][0] = load8(qp);
        aQ[qs][1] = load8(qp + 32);
    }

    bf16x8 bOnes;
#pragma unroll
    for (int i = 0; i < 8; i++) bOnes[i] = (bf16)1.0f;

    floatx4 Oacc[2][4] = {};
    floatx4 Lacc[2] = {};

    const int srow = lane >> 3, sseg = (lane & 7) ^ srow;
    const bf16* Kg = Kmat + (size_t)srow * DM + h * 64 + sseg * 8;
    const bf16* Vg = Vt + (size_t)h * 64 * 4096 + (size_t)srow * 4096 + sseg * 8;

    auto stage = [&](int buf, int kb2) {
#pragma unroll
        for (int c = 2 * wv; c < 2 * wv + 2; c++) {
            gload_lds(Kg + (size_t)(kb2 + c * 8) * DM, &Ks[buf][c * 8][0]);
            gload_lds(Vg + (size_t)(c * 8) * 4096 + kb2, &Vs[buf][c * 8][0]);
        }
    };

    const float C_SCALE = 0.18033688011112043f;  // 0.125 * log2(e)
    const float C_BIAS = 23.083120654223415f;    // 16 * log2(e)
    const int sw = lo & 7;

    stage(0, 0);
    for (int kb2 = 0; kb2 < 4096; kb2 += 64) {
        const int buf = (kb2 >> 6) & 1;
        __syncthreads();
        if (kb2 + 64 < 4096) stage(buf ^ 1, kb2 + 64);

        // ---- S^T tile: rows=keys (t*16+quad*4+r), cols=q (lo) ----
        floatx4 st[2][4];
#pragma unroll
        for (int t = 0; t < 4; t++) {
            const bf16* krow = &Ks[buf][t * 16 + lo][0];
            const bf16x8 aK0 = load8(krow + ((quad ^ sw) * 8));
            const bf16x8 aK1 = load8(krow + (((quad + 4) ^ sw) * 8));
#pragma unroll
            for (int qs = 0; qs < 2; qs++) {
                floatx4 z = {};
                z = MFMA(aK0, aQ[qs][0], z);
                st[qs][t] = MFMA(aK1, aQ[qs][1], z);
            }
        }

        // ---- p = 2^(s*scale - bias); 4 consecutive keys/lane -> b64 write ----
#pragma unroll
        for (int qs = 0; qs < 2; qs++)
#pragma unroll
            for (int t = 0; t < 4; t++) {
                bf16x4 pp;
#pragma unroll
                for (int r = 0; r < 4; r++)
                    pp[r] = (bf16)exp2f(fmaf(st[qs][t][r], C_SCALE, -C_BIAS));
                *(bf16x4*)(&Ps[wv][qs][lo][t * 16 + quad * 4]) = pp;
            }

        // ---- PV + l-accum: O[q][d] += P V^T; l[q] += P*ones ----
#pragma unroll
        for (int kk = 0; kk < 2; kk++) {
            bf16x8 aP[2];
            aP[0] = load8(&Ps[wv][0][lo][kk * 32 + quad * 8]);
            aP[1] = load8(&Ps[wv][1][lo][kk * 32 + quad * 8]);
            Lacc[0] = MFMA(aP[0], bOnes, Lacc[0]);
            Lacc[1] = MFMA(aP[1], bOnes, Lacc[1]);
#pragma unroll
            for (int nt = 0; nt < 4; nt++) {
                const bf16x8 bV = load8(&Vs[buf][nt * 16 + lo][(((kk * 4 + quad) ^ sw) * 8)]);
                Oacc[0][nt] = MFMA(aP[0], bV, Oacc[0][nt]);
                Oacc[1][nt] = MFMA(aP[1], bV, Oacc[1][nt]);
            }
        }
    }

    // ---- epilogue: l is already per-(q-row) in Lacc C-layout; divide, store ----
#pragma unroll
    for (int qs = 0; qs < 2; qs++)
#pragma unroll
        for (int r = 0; r < 4; r++) {
            const float inv = 1.0f / Lacc[qs][r];
#pragma unroll
            for (int nt = 0; nt < 4; nt++) {
                O[(size_t)(q0 + qs * 16 + quad * 4 + r) * DM + h * 64 + nt * 16 + lo] =
                    (bf16)(Oacc[qs][nt][r] * inv);
            }
        }
}

extern "C" void kernel_launch(void* const* d_in, const int* in_sizes, int n_in,
                              void* d_out, int out_size, void* d_ws, size_t ws_size,
                              hipStream_t stream) {
    const float* query = (const float*)d_in[0];
    const float* key_i = (const float*)d_in[1];
    const float* value = (const float*)d_in[2];
    const float* Wq = (const float*)d_in[3];
    const float* bq = (const float*)d_in[4];
    const float* Wk = (const float*)d_in[5];
    const float* bk = (const float*)d_in[6];
    const float* Wv = (const float*)d_in[7];
    const float* bv = (const float*)d_in[8];
    const float* Wo = (const float*)d_in[9];
    const float* bo = (const float*)d_in[10];

    bf16* ws = (bf16*)d_ws;
    const size_t SZ = (size_t)4096 * 1024;  // 4M elems
    const size_t WZ = (size_t)1024 * 1024;  // 1M elems
    // 56 MB layout; O aliases qb (dead after gemm_qkv).
    bf16* qb = ws;                  // 4M
    bf16* kb = ws + SZ;             // 4M
    bf16* vb = ws + 2 * SZ;         // 4M
    bf16* Wqb = ws + 3 * SZ;        // 1M
    bf16* Wkb = ws + 3 * SZ + WZ;   // 1M
    bf16* Wvb = ws + 3 * SZ + 2 * WZ;
    bf16* Wob = ws + 3 * SZ + 3 * WZ;
    bf16* Q = ws + 3 * SZ + 4 * WZ;  // 4M
    bf16* K = Q + SZ;                // 4M
    bf16* Vt = Q + 2 * SZ;           // 4M
    bf16* O = qb;                    // alias

    CvtArgs ca;
    const int SZi = 4096 * 1024, WZi = 1024 * 1024;
    ca.src[0] = query; ca.dst[0] = qb;  ca.n[0] = SZi;
    ca.src[1] = key_i; ca.dst[1] = kb;  ca.n[1] = SZi;
    ca.src[2] = value; ca.dst[2] = vb;  ca.n[2] = SZi;
    ca.src[3] = Wq;    ca.dst[3] = Wqb; ca.n[3] = WZi;
    ca.src[4] = Wk;    ca.dst[4] = Wkb; ca.n[4] = WZi;
    ca.src[5] = Wv;    ca.dst[5] = Wvb; ca.n[5] = WZi;
    ca.src[6] = Wo;    ca.dst[6] = Wob; ca.n[6] = WZi;
    cvt_bf16<<<dim3(2048, 7), 256, 0, stream>>>(ca);

    gemm_qkv<<<dim3(8, 32, 3), 256, 0, stream>>>(qb, kb, vb, Wqb, Wkb, Wvb,
                                                 bq, bk, bv, Q, K, Vt);
    flash_attn5<<<dim3(16, 32), 256, 0, stream>>>(Q, K, Vt, O);
    gemm_o<<<dim3(8, 32), 256, 0, stream>>>(O, Wob, bo, (float*)d_out);
}